// Round 6
// baseline (125.339 us; speedup 1.0000x reference)
//
#include <hip/hip_runtime.h>

#define N_FEAT 1024
#define N_LAYER 4
#define RPG 4              // rows per LDS group/tile (16 KB)
#define GPB 4              // groups per block
#define AS1 __attribute__((address_space(1)))
#define AS3 __attribute__((address_space(3)))

// Algebra: xi = A_i*x0 + C_i, C_i = sum_{j<i} b_j (row-independent).
//   p_i = <x0,w_i>, e_i = <C_i,w_i>; A_{i+1} = A_i*(1+p_i) + e_i;
//   out = A_4*x0 + csum.
//
// Occupancy experiment: R0/R4/R5 all ran 8 waves/CU (64KB LDS or 210 VGPR)
// and all plateau at ~4.4 TB/s; pipeline choreography (sync barrier vs
// counted vmcnt) was proven irrelevant (R4==R5). Hypothesis: 2 lockstep
// waves/SIMD leave read-issue slots empty in aligned bursts. This version
// doubles residency at IDENTICAL per-byte overhead: 16KB tiles (2x16 dbuf),
// 1024 blocks -> 4 blocks/CU -> 16 waves/CU. csum moves to LDS (4KB) to
// keep VGPR <= 128 for the __launch_bounds__(256,4) cap. Wave w stages and
// consumes only row w of each group -> still barrier-free, wave-local
// counted vmcnt: steady wait vmcnt(8) (= S(t-1) 4 + L(t+1) 4), edges
// vmcnt(4). In-order vmcnt retirement (m135) makes counts exact; anything
// the compiler issues in between only makes the wait stricter.
__global__ __launch_bounds__(256, 4) void crossnet_kernel(
    const float* __restrict__ x,
    const float* __restrict__ weight_w,
    const float* __restrict__ weight_b,
    float* __restrict__ out,
    int n_rows) {
  const int wave = threadIdx.x >> 6;   // 0..3
  const int lane = threadIdx.x & 63;

  __shared__ float buf[2][RPG * N_FEAT];   // 2 x 16 KB
  __shared__ float4 csum_lds[4 * 64];      // 4 KB

  // ---- hoisted once per kernel: w in regs, e scalars, csum -> LDS ----
  float4 w[4][N_LAYER];
  float e[N_LAYER] = {0.f, 0.f, 0.f, 0.f};
#pragma unroll
  for (int c = 0; c < 4; ++c) {
#pragma unroll
    for (int i = 0; i < N_LAYER; ++i)
      w[c][i] = ((const float4*)(weight_w + i * N_FEAT))[c * 64 + lane];
    float4 cum = make_float4(0.f, 0.f, 0.f, 0.f);
#pragma unroll
    for (int i = 0; i < N_LAYER; ++i) {
      if (i > 0)
        e[i] += cum.x * w[c][i].x + cum.y * w[c][i].y +
                cum.z * w[c][i].z + cum.w * w[c][i].w;
      const float4 b = ((const float4*)(weight_b + i * N_FEAT))[c * 64 + lane];
      cum.x += b.x; cum.y += b.y; cum.z += b.z; cum.w += b.w;
    }
    // all 4 waves write bit-identical values: benign race, no barrier needed
    csum_lds[c * 64 + lane] = cum;
  }
#pragma unroll
  for (int off = 32; off > 0; off >>= 1)
#pragma unroll
    for (int i = 1; i < N_LAYER; ++i) e[i] += __shfl_xor(e[i], off, 64);

  const int row0 = blockIdx.x * (RPG * GPB);
  if (row0 >= n_rows) return;

  // Wave w stages its own row w of the group (4 x 16B/lane = 4 KB).
  auto stage = [&](int bsel, int grow) {
#pragma unroll
    for (int c = 0; c < 4; ++c) {
      const float* gsrc =
          x + (size_t)(grow + wave) * N_FEAT + (c * 64 + lane) * 4;
      float* ldst = &buf[bsel][wave * N_FEAT + c * 256];
      __builtin_amdgcn_global_load_lds((const AS1 unsigned int*)gsrc,
                                       (AS3 unsigned int*)ldst, 16, 0, 0);
    }
  };

  stage(0, row0);

#pragma unroll
  for (int t = 0; t < GPB; ++t) {
    const int grow = row0 + t * RPG;

    __builtin_amdgcn_sched_barrier(0);
    if (t + 1 < GPB) stage((t + 1) & 1, grow + RPG);

    // Wait for this group's own staging (wave-local; no block barrier).
    if (t == 0 || t == GPB - 1) {
      asm volatile("s_waitcnt vmcnt(4)" ::: "memory");
    } else {
      asm volatile("s_waitcnt vmcnt(8)" ::: "memory");
    }
    __builtin_amdgcn_sched_barrier(0);

    const float* B = buf[t & 1];

    // ---- dot phase: read own row from LDS, hold xv in regs ----
    float4 xv[4];
    float p[N_LAYER] = {0.f, 0.f, 0.f, 0.f};
#pragma unroll
    for (int c = 0; c < 4; ++c) {
      xv[c] = *(const float4*)&B[wave * N_FEAT + (c * 64 + lane) * 4];
#pragma unroll
      for (int i = 0; i < N_LAYER; ++i)
        p[i] += xv[c].x * w[c][i].x + xv[c].y * w[c][i].y +
                xv[c].z * w[c][i].z + xv[c].w * w[c][i].w;
    }

    // ---- butterfly: 4 p-values, 6 steps ----
#pragma unroll
    for (int off = 32; off > 0; off >>= 1)
#pragma unroll
      for (int i = 0; i < N_LAYER; ++i) p[i] += __shfl_xor(p[i], off, 64);

    // ---- recurrence + store (xv in regs: x read from HBM exactly once) ----
    float A = 1.f;
#pragma unroll
    for (int i = 0; i < N_LAYER; ++i) A += A * p[i] + e[i];

    const size_t row = grow + wave;
#pragma unroll
    for (int c = 0; c < 4; ++c) {
      const float4 cs = csum_lds[c * 64 + lane];
      float4 o;
      o.x = fmaf(xv[c].x, A, cs.x);
      o.y = fmaf(xv[c].y, A, cs.y);
      o.z = fmaf(xv[c].z, A, cs.z);
      o.w = fmaf(xv[c].w, A, cs.w);
      ((float4*)out)[row * 256 + c * 64 + lane] = o;
    }
  }
}

extern "C" void kernel_launch(void* const* d_in, const int* in_sizes, int n_in,
                              void* d_out, int out_size, void* d_ws, size_t ws_size,
                              hipStream_t stream) {
  const float* x = (const float*)d_in[0];
  const float* ww = (const float*)d_in[1];
  const float* wb = (const float*)d_in[2];
  float* out = (float*)d_out;

  const int n_rows = in_sizes[0] / N_FEAT;            // 16384
  const int rows_per_block = RPG * GPB;               // 16
  const int n_blocks = (n_rows + rows_per_block - 1) / rows_per_block;  // 1024
  crossnet_kernel<<<n_blocks, 256, 0, stream>>>(x, ww, wb, out, n_rows);
}